// Round 4
// baseline (771.520 us; speedup 1.0000x reference)
//
#include <hip/hip_runtime.h>
#include <math.h>

// Problem: MultiHeadAttentionEinsum  B=2, S=2048, E=1024, H=16, D=64
// Inputs are fp32 (confirmed: bf16 interpretation NaNs, fp32 path is finite);
// runtime dtype sniffing kept as insurance. Internal compute bf16 MFMA.
// Workspace layout (ushort/bf16), total 32 MB + flag:
//   Q  [B,H,S,D]  4,194,304 elems
//   K  [B,H,S,D]  4,194,304
//   Vt [B,H,D,S]  4,194,304   (V transposed per head for contiguous PV frags)
//   AO [B,S,E]    4,194,304   (attention output, pre out-projection; ALWAYS bf16)
//   flag (int)    dtype flag: 1 = bf16 inputs, 0 = fp32 inputs

#define EMBED 1024
#define SEQ   2048
#define BATCH 2
#define NH    16
#define HD    64

typedef __attribute__((ext_vector_type(8))) short bf16x8;
typedef __attribute__((ext_vector_type(4))) float f32x4;

#define M_INIT (-3.0e38f)

__device__ inline unsigned short f2bf(float f) {
  unsigned int u = __builtin_bit_cast(unsigned int, f);
  u += 0x7fffu + ((u >> 16) & 1u);          // round-to-nearest-even
  return (unsigned short)(u >> 16);
}
__device__ inline float bf2f(unsigned short s) {
  unsigned int u = ((unsigned int)s) << 16;
  return __builtin_bit_cast(float, u);
}

// Sniff input dtype from first 256 u32 words of xq. bf16 data: low u16 of each
// word is a bf16 value ~N(0,1) -> exponent field in [0x70,0x8F] (~100% hit).
// fp32 data: low u16 is uniform mantissa bits -> ~12.5% hit.
__global__ void detect_kernel(const unsigned int* __restrict__ xq, int* __restrict__ flag) {
  __shared__ int cnt[256];
  int t = threadIdx.x;
  unsigned int w = xq[t];
  unsigned int e = (w >> 7) & 0xFFu;
  cnt[t] = (e >= 0x70u && e <= 0x8Fu) ? 1 : 0;
  __syncthreads();
  for (int s = 128; s > 0; s >>= 1) {
    if (t < s) cnt[t] += cnt[t + s];
    __syncthreads();
  }
  if (t == 0) *flag = (cnt[0] >= 160) ? 1 : 0;
}

__device__ inline bf16x8 load8(const void* p, int idx, bool isbf) {
  if (isbf) return *(const bf16x8*)((const unsigned short*)p + idx);
  const float* f = (const float*)p + idx;
  bf16x8 r;
#pragma unroll
  for (int i = 0; i < 8; ++i) r[i] = (short)f2bf(f[i]);
  return r;
}

// C[m][n] = sum_k A[m][k] * Bw[n][k]   (A: 4096x1024, Bw: 1024x1024, row-major)
// mode 0: out[m][n] row-major [B,S,E] + bias[n]; A is ALWAYS bf16 (AO buffer)
// mode 1: out as [B,H,S,D] bf16   (Q/K staging); A follows flag
// mode 2: out as [B,H,D,S] bf16   (V transposed staging); A follows flag
__global__ __launch_bounds__(256) void gemm_bt(
    const void* __restrict__ A,
    const void* __restrict__ Bw,
    const void* __restrict__ bias,
    void* __restrict__ out,
    const int* __restrict__ flagp,
    int mode)
{
  const bool isbf = (*flagp != 0);
  const bool a_isbf = isbf || (mode == 0);  // AO staging buffer is always bf16
  const int lane = threadIdx.x & 63;
  const int wave = threadIdx.x >> 6;
  const int tile = blockIdx.x * 4 + wave;   // 4096 tiles: 256 row-tiles x 16 col-tiles
  const int mt = tile >> 4;
  const int nt = tile & 15;
  const int q = lane >> 4;                  // quad 0..3
  const int c = lane & 15;
  const int m0 = mt * 16;
  const int n0 = nt * 64;

  f32x4 acc[4];
#pragma unroll
  for (int t = 0; t < 4; ++t) acc[t] = (f32x4){0.f, 0.f, 0.f, 0.f};

  for (int k0 = 0; k0 < EMBED; k0 += 32) {
    bf16x8 a = load8(A, (m0 + c) * EMBED + k0 + q * 8, a_isbf);
#pragma unroll
    for (int t = 0; t < 4; ++t) {
      bf16x8 b = load8(Bw, (n0 + t * 16 + c) * EMBED + k0 + q * 8, isbf);
      acc[t] = __builtin_amdgcn_mfma_f32_16x16x32_bf16(a, b, acc[t], 0, 0, 0);
    }
  }

#pragma unroll
  for (int t = 0; t < 4; ++t) {
#pragma unroll
    for (int r = 0; r < 4; ++r) {
      float v = acc[t][r];
      int row = m0 + q * 4 + r;             // m
      int col = n0 + t * 16 + c;            // n
      if (mode == 0) {
        v += isbf ? bf2f(((const unsigned short*)bias)[col])
                  : ((const float*)bias)[col];
        if (isnan(v)) v = 777.0f;           // marker: NaN reached out-projection
        if (isbf) ((unsigned short*)out)[row * EMBED + col] = f2bf(v);
        else      ((float*)out)[row * EMBED + col] = v;
      } else {
        if (isnan(v)) v = 55.0f;            // marker: NaN in QKV projection
        int b = row >> 11, s = row & 2047, h = col >> 6, d = col & 63;
        if (mode == 1)
          ((unsigned short*)out)[(((b * NH + h) * SEQ) + s) * HD + d] = f2bf(v);
        else
          ((unsigned short*)out)[(((b * NH + h) * HD) + d) * SEQ + s] = f2bf(v);
      }
    }
  }
}

// Flash attention. Grid (32, 16, 2), block 256 (4 waves x 16 q-rows).
// Scores computed transposed: S^T = K_tile * Q_tile^T so per-q softmax state is in lane&15.
// P -> A-operand via LDS round-trip with an explicit barrier.
__global__ __launch_bounds__(256) void attn_kernel(
    const unsigned short* __restrict__ Qb,
    const unsigned short* __restrict__ Kb,
    const unsigned short* __restrict__ Vtb,
    unsigned short* __restrict__ Ob)
{
  __shared__ __align__(16) unsigned short Kt[32][72];       // 32 keys x 64 d; row 144B
  __shared__ __align__(16) unsigned short Vt[64][56];       // 64 d x 32 keys; row 112B
  __shared__ __align__(16) unsigned short Pt[4 * 16][40];   // per-wave 16 qrows x 32 keys; row 80B

  const int tid = threadIdx.x;
  const int lane = tid & 63;
  const int wave = tid >> 6;
  const int q = lane >> 4;                 // quad
  const int c = lane & 15;
  const int b = blockIdx.z, h = blockIdx.y;
  const int q0 = blockIdx.x * 64 + wave * 16;

  const unsigned short* Qh = Qb + ((size_t)(b * NH + h) * SEQ) * HD;
  const unsigned short* Kh = Kb + ((size_t)(b * NH + h) * SEQ) * HD;
  const unsigned short* Vh = Vtb + ((size_t)(b * NH + h) * HD) * SEQ;

  // Q fragments (B-operand: n = lane&15 = q-row, k(=d) = quad*8+j), held all kernel.
  bf16x8 qf0 = *(const bf16x8*)(Qh + (q0 + c) * HD + q * 8);
  bf16x8 qf1 = *(const bf16x8*)(Qh + (q0 + c) * HD + 32 + q * 8);

  float m_run = M_INIT;
  float l_run = 0.f;
  f32x4 o[4];
#pragma unroll
  for (int t = 0; t < 4; ++t) o[t] = (f32x4){0.f, 0.f, 0.f, 0.f};

  const float cs = 0.125f * 1.44269504088896340736f;   // (1/sqrt(64)) * log2(e)

  const int skey = tid >> 3;        // 0..31
  const int sd   = (tid & 7) * 8;   // d offset
  const int vd   = tid >> 2;        // 0..63
  const int vk   = (tid & 3) * 8;   // key offset

  for (int kt = 0; kt < SEQ / 32; ++kt) {
    __syncthreads();
    *(bf16x8*)(&Kt[skey][sd]) = *(const bf16x8*)(Kh + (kt * 32 + skey) * HD + sd);
    *(bf16x8*)(&Vt[vd][vk])   = *(const bf16x8*)(Vh + vd * SEQ + kt * 32 + vk);
    __syncthreads();

    // scores: two 16-key subtiles; C = S^T[key_local=quad*4+reg][qrow=lane&15]
    float p[8];
    float mloc = M_INIT;
#pragma unroll
    for (int sub = 0; sub < 2; ++sub) {
      bf16x8 k0f = *(const bf16x8*)(&Kt[sub * 16 + c][q * 8]);
      bf16x8 k1f = *(const bf16x8*)(&Kt[sub * 16 + c][32 + q * 8]);
      f32x4 z = {0.f, 0.f, 0.f, 0.f};
      z = __builtin_amdgcn_mfma_f32_16x16x32_bf16(k0f, qf0, z, 0, 0, 0);
      z = __builtin_amdgcn_mfma_f32_16x16x32_bf16(k1f, qf1, z, 0, 0, 0);
#pragma unroll
      for (int r = 0; r < 4; ++r) {
        float sv = z[r] * cs;
        p[sub * 4 + r] = sv;
        mloc = fmaxf(mloc, sv);
      }
    }
    mloc = fmaxf(mloc, __shfl_xor(mloc, 16));
    mloc = fmaxf(mloc, __shfl_xor(mloc, 32));
    float m_new = fmaxf(m_run, mloc);
    float alpha = exp2f(m_run - m_new);   // first tile: exp2f(-3e38) == 0
    float rs = 0.f;
#pragma unroll
    for (int i = 0; i < 8; ++i) { p[i] = exp2f(p[i] - m_new); rs += p[i]; }
    rs += __shfl_xor(rs, 16);
    rs += __shfl_xor(rs, 32);
    l_run = l_run * alpha + rs;
    m_run = m_new;

    float af[4];
#pragma unroll
    for (int r = 0; r < 4; ++r) af[r] = __shfl(alpha, q * 4 + r);
#pragma unroll
    for (int t = 0; t < 4; ++t) {
      o[t][0] *= af[0]; o[t][1] *= af[1]; o[t][2] *= af[2]; o[t][3] *= af[3];
    }

    // P transform: C-layout write -> barrier -> A-layout read (m120 pattern).
    unsigned short (*Pw)[40] = &Pt[wave * 16];
#pragma unroll
    for (int sub = 0; sub < 2; ++sub)
#pragma unroll
      for (int r = 0; r < 4; ++r)
        Pw[c][sub * 16 + q * 4 + r] = f2bf(p[sub * 4 + r]);
    __syncthreads();

    bf16x8 pf = *(const bf16x8*)(&Pw[c][q * 8]);   // P[qrow=c][key=quad*8+j]

    // PV: O[qrow][d] += P * V ; B-operand: V[key=quad*8+j][d=16t+lane&15]
#pragma unroll
    for (int t = 0; t < 4; ++t) {
      bf16x8 vf = *(const bf16x8*)(&Vt[t * 16 + c][q * 8]);
      o[t] = __builtin_amdgcn_mfma_f32_16x16x32_bf16(pf, vf, o[t], 0, 0, 0);
    }
  }

  float lf[4];
#pragma unroll
  for (int r = 0; r < 4; ++r) lf[r] = 1.f / __shfl(l_run, q * 4 + r);

#pragma unroll
  for (int t = 0; t < 4; ++t) {
#pragma unroll
    for (int r = 0; r < 4; ++r) {
      int srow = q0 + q * 4 + r;
      int col = h * HD + t * 16 + c;
      float val = o[t][r] * lf[r];
      if (isnan(val)) val = 77.0f;          // marker: NaN in attention
      Ob[((size_t)(b * SEQ + srow)) * EMBED + col] = f2bf(val);
    }
  }
}

extern "C" void kernel_launch(void* const* d_in, const int* in_sizes, int n_in,
                              void* d_out, int out_size, void* d_ws, size_t ws_size,
                              hipStream_t stream) {
  const void* xq = d_in[0];
  const void* xk = d_in[1];
  const void* xv = d_in[2];
  const void* Wq = d_in[3];
  const void* Wk = d_in[4];
  const void* Wv = d_in[5];
  const void* Wo = d_in[6];
  const void* bo = d_in[7];

  const size_t NEL = (size_t)BATCH * SEQ * EMBED;   // 4,194,304
  unsigned short* Q  = (unsigned short*)d_ws;
  unsigned short* K  = Q + NEL;
  unsigned short* Vt = K + NEL;
  unsigned short* AO = Vt + NEL;
  int* flag = (int*)(AO + NEL);

  detect_kernel<<<1, 256, 0, stream>>>((const unsigned int*)xq, flag);

  dim3 gblk(1024, 1, 1);
  gemm_bt<<<gblk, 256, 0, stream>>>(xq, Wq, nullptr, Q, flag, 1);
  gemm_bt<<<gblk, 256, 0, stream>>>(xk, Wk, nullptr, K, flag, 1);
  gemm_bt<<<gblk, 256, 0, stream>>>(xv, Wv, nullptr, Vt, flag, 2);
  attn_kernel<<<dim3(32, NH, BATCH), 256, 0, stream>>>(Q, K, Vt, AO);
  gemm_bt<<<gblk, 256, 0, stream>>>(AO, Wo, bo, d_out, flag, 0);
}

// Round 5
// 305.533 us; speedup vs baseline: 2.5252x; 2.5252x over previous
//
#include <hip/hip_runtime.h>
#include <math.h>

// MultiHeadAttentionEinsum  B=2, S=2048, E=1024, H=16, D=64. Inputs fp32
// (confirmed round 3; bf16-sniff kept as insurance). Compute bf16 MFMA.
//
// Fast path (ws >= 58.7MB): pack all fp32->bf16 once, then m97-style
// 128x64-tile LDS GEMMs with global_load_lds(16B). AO aliases Xq (dead).
// Fallback (small ws): round-3 proven direct-global GEMM path.

#define EMBED 1024
#define SEQ   2048
#define BATCH 2
#define NH    16
#define HD    64
#define BM 128
#define BN 64
#define BK 32

typedef __attribute__((ext_vector_type(8))) short bf16x8;
typedef __attribute__((ext_vector_type(4))) float f32x4;

#define M_INIT (-3.0e38f)

__device__ inline unsigned short f2bf(float f) {
  unsigned int u = __builtin_bit_cast(unsigned int, f);
  u += 0x7fffu + ((u >> 16) & 1u);
  return (unsigned short)(u >> 16);
}
__device__ inline float bf2f(unsigned short s) {
  unsigned int u = ((unsigned int)s) << 16;
  return __builtin_bit_cast(float, u);
}

// async global->LDS, 16B per lane; LDS dest = wave-uniform base + lane*16.
__device__ inline void async_cp16(const void* g, void* l) {
  __builtin_amdgcn_global_load_lds(
      (const __attribute__((address_space(1))) unsigned int*)g,
      (__attribute__((address_space(3))) unsigned int*)l, 16, 0, 0);
}

// ---- dtype sniff (bf16 data: low u16 of u32 word has sane bf16 exponent) ----
__global__ void detect_kernel(const unsigned int* __restrict__ xq, int* __restrict__ flag) {
  __shared__ int cnt[256];
  int t = threadIdx.x;
  unsigned int w = xq[t];
  unsigned int e = (w >> 7) & 0xFFu;
  cnt[t] = (e >= 0x70u && e <= 0x8Fu) ? 1 : 0;
  __syncthreads();
  for (int s = 128; s > 0; s >>= 1) {
    if (t < s) cnt[t] += cnt[t + s];
    __syncthreads();
  }
  if (t == 0) *flag = (cnt[0] >= 160) ? 1 : 0;
}

// ---- fused fp32->bf16 pack of xq,xk,xv (4.19M el) + Wq,Wk,Wv,Wo (1.05M el) ----
struct PackPtrs {
  const void* src[7];
  unsigned short* dst[7];
};
__global__ __launch_bounds__(256) void pack_all(PackPtrs p, const int* __restrict__ flagp) {
  const bool isbf = (*flagp != 0);
  int ci = blockIdx.x * 256 + threadIdx.x;        // 8-elem chunk, 2,097,152 total
  int t, rel;
  if (ci < 1572864) { t = ci / 524288; rel = ci - t * 524288; }
  else { int r = ci - 1572864; int w = r / 131072; t = 3 + w; rel = r - w * 131072; }
  size_t off = (size_t)rel * 8;
  unsigned short* d = p.dst[t] + off;
  if (isbf) {
    *(bf16x8*)d = *(const bf16x8*)((const unsigned short*)p.src[t] + off);
  } else {
    const float* s = (const float*)p.src[t] + off;
    bf16x8 v;
#pragma unroll
    for (int e = 0; e < 8; ++e) v[e] = (short)f2bf(s[e]);
    *(bf16x8*)d = v;
  }
}

// ---- m97-style tiled GEMM: C[m][n] = sum_k A[m][k]*Bw[n][k], A/Bw bf16 row-major ----
// grid (4096/BM=32, 1024/BN=16). 256 thr = 4 waves in 2x2; wave tile 64x32.
// mode 0: out[m][n] (+bias), fp32 or bf16 per flag
// mode 1: out [B,H,S,D] bf16
// mode 2: out [B,H,D,S] bf16 via LDS-transpose epilogue (coalesced stores)
__global__ __launch_bounds__(256) void gemm128(
    const unsigned short* __restrict__ A,
    const unsigned short* __restrict__ Bw,
    const void* __restrict__ bias,
    void* __restrict__ out,
    const int* __restrict__ flagp,
    int mode)
{
  __shared__ __align__(16) unsigned short As[BM * BK];        // 8 KB
  __shared__ __align__(16) unsigned short Bs[BN * BK];        // 4 KB
  __shared__ __align__(16) unsigned short Ts[BM * (BN + 2)];  // 16.5 KB (mode 2)

  const int tid = threadIdx.x;
  const int lane = tid & 63;
  const int wave = tid >> 6;
  const int wm = wave >> 1, wn = wave & 1;
  const int q = lane >> 4, c = lane & 15;
  const int m0 = blockIdx.x * BM;
  const int n0 = blockIdx.y * BN;

  f32x4 acc[4][2];
#pragma unroll
  for (int i = 0; i < 4; ++i)
#pragma unroll
    for (int j = 0; j < 2; ++j) acc[i][j] = (f32x4){0.f, 0.f, 0.f, 0.f};

  for (int k0 = 0; k0 < EMBED; k0 += BK) {
    __syncthreads();
    // A tile 128x32 = 512 16B-chunks; thread covers chunks tid, tid+256.
#pragma unroll
    for (int jj = 0; jj < 2; ++jj) {
      int ci = jj * 256 + tid;
      async_cp16(A + (size_t)(m0 + (ci >> 2)) * EMBED + k0 + (ci & 3) * 8,
                 (void*)(As + (jj * 256 + wave * 64) * 8));
    }
    // B tile 64x32 = 256 chunks; thread covers chunk tid.
    async_cp16(Bw + (size_t)(n0 + (tid >> 2)) * EMBED + k0 + (tid & 3) * 8,
               (void*)(Bs + wave * 64 * 8));
    __syncthreads();   // compiler drains vmcnt before s_barrier

    bf16x8 af[4], bfr[2];
#pragma unroll
    for (int i = 0; i < 4; ++i)
      af[i] = *(const bf16x8*)(As + (wm * 64 + i * 16 + c) * BK + q * 8);
#pragma unroll
    for (int j = 0; j < 2; ++j)
      bfr[j] = *(const bf16x8*)(Bs + (wn * 32 + j * 16 + c) * BK + q * 8);
#pragma unroll
    for (int i = 0; i < 4; ++i)
#pragma unroll
      for (int j = 0; j < 2; ++j)
        acc[i][j] = __builtin_amdgcn_mfma_f32_16x16x32_bf16(af[i], bfr[j], acc[i][j], 0, 0, 0);
  }

  const bool isbf = (*flagp != 0);

  if (mode == 2) {
    // transpose 128(s) x 64(d) tile through LDS, store Vt[B,H,D,S] coalesced
    __syncthreads();
#pragma unroll
    for (int i = 0; i < 4; ++i)
#pragma unroll
      for (int j = 0; j < 2; ++j)
#pragma unroll
        for (int r = 0; r < 4; ++r)
          Ts[(wm * 64 + i * 16 + q * 4 + r) * (BN + 2) + wn * 32 + j * 16 + c] =
              f2bf(acc[i][j][r]);
    __syncthreads();
    int d = tid >> 2;             // 0..63 (local == global, BN==HD)
    int sb = (tid & 3) * 32;
    int b = m0 >> 11, s0l = m0 & 2047;
    int h = blockIdx.y;           // BN=64 => one head per block column
    unsigned short* dst = (unsigned short*)out +
        (size_t)((b * NH + h) * HD + d) * SEQ + s0l + sb;
#pragma unroll
    for (int g = 0; g < 4; ++g) {
      bf16x8 v;
#pragma unroll
      for (int e = 0; e < 8; ++e) v[e] = (short)Ts[(sb + g * 8 + e) * (BN + 2) + d];
      *(bf16x8*)(dst + g * 8) = v;
    }
  } else {
#pragma unroll
    for (int i = 0; i < 4; ++i)
#pragma unroll
      for (int j = 0; j < 2; ++j)
#pragma unroll
        for (int r = 0; r < 4; ++r) {
          int m = m0 + wm * 64 + i * 16 + q * 4 + r;
          int col = n0 + wn * 32 + j * 16 + c;
          float v = acc[i][j][r];
          if (mode == 0) {
            v += isbf ? bf2f(((const unsigned short*)bias)[col])
                      : ((const float*)bias)[col];
            if (isbf) ((unsigned short*)out)[(size_t)m * EMBED + col] = f2bf(v);
            else      ((float*)out)[(size_t)m * EMBED + col] = v;
          } else {
            int b = m >> 11, s = m & 2047, h = col >> 6, d = col & 63;
            ((unsigned short*)out)[(size_t)((b * NH + h) * SEQ + s) * HD + d] = f2bf(v);
          }
        }
  }
}

// ---- fallback GEMM (round-3 proven, direct global loads) ----
__device__ inline bf16x8 load8(const void* p, int idx, bool isbf) {
  if (isbf) return *(const bf16x8*)((const unsigned short*)p + idx);
  const float* f = (const float*)p + idx;
  bf16x8 r;
#pragma unroll
  for (int i = 0; i < 8; ++i) r[i] = (short)f2bf(f[i]);
  return r;
}
__global__ __launch_bounds__(256) void gemm_bt(
    const void* __restrict__ A, const void* __restrict__ Bw,
    const void* __restrict__ bias, void* __restrict__ out,
    const int* __restrict__ flagp, int mode)
{
  const bool isbf = (*flagp != 0);
  const bool a_isbf = isbf || (mode == 0);
  const int lane = threadIdx.x & 63;
  const int wave = threadIdx.x >> 6;
  const int tile = blockIdx.x * 4 + wave;
  const int mt = tile >> 4, nt = tile & 15;
  const int q = lane >> 4, c = lane & 15;
  const int m0 = mt * 16, n0 = nt * 64;

  f32x4 acc[4];
#pragma unroll
  for (int t = 0; t < 4; ++t) acc[t] = (f32x4){0.f, 0.f, 0.f, 0.f};

  for (int k0 = 0; k0 < EMBED; k0 += 32) {
    bf16x8 a = load8(A, (m0 + c) * EMBED + k0 + q * 8, a_isbf);
#pragma unroll
    for (int t = 0; t < 4; ++t) {
      bf16x8 b = load8(Bw, (n0 + t * 16 + c) * EMBED + k0 + q * 8, isbf);
      acc[t] = __builtin_amdgcn_mfma_f32_16x16x32_bf16(a, b, acc[t], 0, 0, 0);
    }
  }
#pragma unroll
  for (int t = 0; t < 4; ++t)
#pragma unroll
    for (int r = 0; r < 4; ++r) {
      float v = acc[t][r];
      int row = m0 + q * 4 + r, col = n0 + t * 16 + c;
      if (mode == 0) {
        v += isbf ? bf2f(((const unsigned short*)bias)[col]) : ((const float*)bias)[col];
        if (isbf) ((unsigned short*)out)[row * EMBED + col] = f2bf(v);
        else      ((float*)out)[row * EMBED + col] = v;
      } else {
        int b = row >> 11, s = row & 2047, h = col >> 6, d = col & 63;
        if (mode == 1) ((unsigned short*)out)[(((b * NH + h) * SEQ) + s) * HD + d] = f2bf(v);
        else           ((unsigned short*)out)[(((b * NH + h) * HD) + d) * SEQ + s] = f2bf(v);
      }
    }
}

// ---- flash attention (unchanged from passing round) ----
__global__ __launch_bounds__(256) void attn_kernel(
    const unsigned short* __restrict__ Qb,
    const unsigned short* __restrict__ Kb,
    const unsigned short* __restrict__ Vtb,
    unsigned short* __restrict__ Ob)
{
  __shared__ __align__(16) unsigned short Kt[32][72];
  __shared__ __align__(16) unsigned short Vt[64][56];
  __shared__ __align__(16) unsigned short Pt[4 * 16][40];

  const int tid = threadIdx.x;
  const int lane = tid & 63;
  const int wave = tid >> 6;
  const int q = lane >> 4, c = lane & 15;
  const int b = blockIdx.z, h = blockIdx.y;
  const int q0 = blockIdx.x * 64 + wave * 16;

  const unsigned short* Qh = Qb + ((size_t)(b * NH + h) * SEQ) * HD;
  const unsigned short* Kh = Kb + ((size_t)(b * NH + h) * SEQ) * HD;
  const unsigned short* Vh = Vtb + ((size_t)(b * NH + h) * HD) * SEQ;

  bf16x8 qf0 = *(const bf16x8*)(Qh + (q0 + c) * HD + q * 8);
  bf16x8 qf1 = *(const bf16x8*)(Qh + (q0 + c) * HD + 32 + q * 8);

  float m_run = M_INIT, l_run = 0.f;
  f32x4 o[4];
#pragma unroll
  for (int t = 0; t < 4; ++t) o[t] = (f32x4){0.f, 0.f, 0.f, 0.f};

  const float cs = 0.125f * 1.44269504088896340736f;

  const int skey = tid >> 3, sd = (tid & 7) * 8;
  const int vd = tid >> 2, vk = (tid & 3) * 8;

  for (int kt = 0; kt < SEQ / 32; ++kt) {
    __syncthreads();
    *(bf16x8*)(&Kt[skey][sd]) = *(const bf16x8*)(Kh + (kt * 32 + skey) * HD + sd);
    *(bf16x8*)(&Vt[vd][vk])   = *(const bf16x8*)(Vh + vd * SEQ + kt * 32 + vk);
    __syncthreads();

    float p[8];
    float mloc = M_INIT;
#pragma unroll
    for (int sub = 0; sub < 2; ++sub) {
      bf16x8 k0f = *(const bf16x8*)(&Kt[sub * 16 + c][q * 8]);
      bf16x8 k1f = *(const bf16x8*)(&Kt[sub * 16 + c][32 + q * 8]);
      f32x4 z = {0.f, 0.f, 0.f, 0.f};
      z = __builtin_amdgcn_mfma_f32_16x16x32_bf16(k0f, qf0, z, 0, 0, 0);
      z = __builtin_amdgcn_mfma_f32_16x16x32_bf16(k1f, qf1, z, 0, 0, 0);
#pragma unroll
      for (int r = 0; r < 4; ++r) {
        float sv = z[r] * cs;
        p[sub * 4 + r] = sv;
        mloc = fmaxf(mloc, sv);
      }
    }
    mloc = fmaxf(mloc, __shfl_xor(mloc, 16));
    mloc = fmaxf(mloc, __shfl_xor(mloc, 32));
    float m_new = fmaxf(m_run, mloc);
    float alpha = exp2f(m_run - m_new);
    float rs = 0.f;
#pragma unroll
    for (int i = 0; i < 8; ++i) { p[i] = exp2f(p[i] - m_new); rs += p[i]; }
    rs += __shfl_xor(rs, 16);
    rs += __shfl_xor(rs, 32);
    l_run = l_run * alpha + rs;
    m_run = m_new;

    float af[4];
#pragma unroll
    for (int r = 0; r < 4; ++r) af[r] = __shfl(alpha, q * 4 + r);
#pragma unroll
    for (int t = 0; t < 4; ++t) {
      o[t][0] *= af[0]; o[t][1] *= af[1]; o[t][2] *= af[2]; o[t][3] *= af[3];
    }

    unsigned short (*Pw)[40] = &Pt[wave * 16];
#pragma unroll
    for (int sub = 0; sub < 2; ++sub)
#pragma unroll
      for (int r = 0; r < 4; ++r)
        Pw[c][sub * 16 + q * 4 + r] = f2bf(p[sub * 4 + r]);
    __syncthreads();

    bf16x8 pf = *(const bf16x8*)(&Pw[c][q * 8]);

#pragma unroll
    for (int t = 0; t < 4; ++t) {
      bf16x8 vf = *(const bf16x8*)(&Vt[t * 16 + c][q * 8]);
      o[t] = __builtin_amdgcn_mfma_f32_16x16x32_bf16(pf, vf, o[t], 0, 0, 0);
    }
  }

  float lf[4];
#pragma unroll
  for (int r = 0; r < 4; ++r) lf[r] = 1.f / __shfl(l_run, q * 4 + r);

#pragma unroll
  for (int t = 0; t < 4; ++t)
#pragma unroll
    for (int r = 0; r < 4; ++r) {
      int srow = q0 + q * 4 + r;
      int col = h * HD + t * 16 + c;
      float val = o[t][r] * lf[r];
      if (isnan(val)) val = 77.0f;
      Ob[((size_t)(b * SEQ + srow)) * EMBED + col] = f2bf(val);
    }
}

extern "C" void kernel_launch(void* const* d_in, const int* in_sizes, int n_in,
                              void* d_out, int out_size, void* d_ws, size_t ws_size,
                              hipStream_t stream) {
  const void* xq = d_in[0]; const void* xk = d_in[1]; const void* xv = d_in[2];
  const void* Wq = d_in[3]; const void* Wk = d_in[4]; const void* Wv = d_in[5];
  const void* Wo = d_in[6]; const void* bo = d_in[7];

  const size_t NEL = (size_t)BATCH * SEQ * EMBED;   // 4,194,304
  const size_t WEL = (size_t)EMBED * EMBED;         // 1,048,576
  unsigned short* base = (unsigned short*)d_ws;

  // fast-path layout
  unsigned short* Xq = base;
  unsigned short* Xk = Xq + NEL;
  unsigned short* Xv = Xk + NEL;
  unsigned short* Wqb = Xv + NEL;
  unsigned short* Wkb = Wqb + WEL;
  unsigned short* Wvb = Wkb + WEL;
  unsigned short* Wob = Wvb + WEL;
  unsigned short* Q  = Wob + WEL;
  unsigned short* K  = Q + NEL;
  unsigned short* Vt = K + NEL;
  unsigned short* AO = Xq;                  // alias: Xq dead after its GEMM
  int* flagF = (int*)(Vt + NEL);
  size_t need = ((char*)(flagF + 16)) - (char*)d_ws;

  if (ws_size >= need) {
    detect_kernel<<<1, 256, 0, stream>>>((const unsigned int*)xq, flagF);
    PackPtrs pp;
    pp.src[0] = xq; pp.src[1] = xk; pp.src[2] = xv;
    pp.src[3] = Wq; pp.src[4] = Wk; pp.src[5] = Wv; pp.src[6] = Wo;
    pp.dst[0] = Xq; pp.dst[1] = Xk; pp.dst[2] = Xv;
    pp.dst[3] = Wqb; pp.dst[4] = Wkb; pp.dst[5] = Wvb; pp.dst[6] = Wob;
    pack_all<<<8192, 256, 0, stream>>>(pp, flagF);
    dim3 gg(32, 16);
    gemm128<<<gg, 256, 0, stream>>>(Xq, Wqb, nullptr, Q, flagF, 1);
    gemm128<<<gg, 256, 0, stream>>>(Xk, Wkb, nullptr, K, flagF, 1);
    gemm128<<<gg, 256, 0, stream>>>(Xv, Wvb, nullptr, Vt, flagF, 2);
    attn_kernel<<<dim3(32, NH, BATCH), 256, 0, stream>>>(Q, K, Vt, AO);
    gemm128<<<gg, 256, 0, stream>>>(AO, Wob, bo, d_out, flagF, 0);
  } else {
    // round-3 proven fallback (33.55 MB)
    unsigned short* Qf  = base;
    unsigned short* Kf  = Qf + NEL;
    unsigned short* Vtf = Kf + NEL;
    unsigned short* AOf = Vtf + NEL;
    int* flag = (int*)(AOf + NEL);
    detect_kernel<<<1, 256, 0, stream>>>((const unsigned int*)xq, flag);
    dim3 gblk(1024, 1, 1);
    gemm_bt<<<gblk, 256, 0, stream>>>(xq, Wq, nullptr, Qf, flag, 1);
    gemm_bt<<<gblk, 256, 0, stream>>>(xk, Wk, nullptr, Kf, flag, 1);
    gemm_bt<<<gblk, 256, 0, stream>>>(xv, Wv, nullptr, Vtf, flag, 2);
    attn_kernel<<<dim3(32, NH, BATCH), 256, 0, stream>>>(Qf, Kf, Vtf, AOf);
    gemm_bt<<<gblk, 256, 0, stream>>>(AOf, Wo, bo, d_out, flag, 0);
  }
}

// Round 6
// 268.895 us; speedup vs baseline: 2.8692x; 1.1363x over previous
//
#include <hip/hip_runtime.h>
#include <math.h>

// MultiHeadAttentionEinsum  B=2, S=2048, E=1024, H=16, D=64. Inputs fp32
// (confirmed round 3; bf16-sniff kept as insurance). Compute bf16 MFMA.
// Fast path: pack fp32->bf16 once, m97-style LDS GEMMs, fused flash attn v2
// (S^T C-layout feeds PV A-operand directly; fixed-shift softmax).

#define EMBED 1024
#define SEQ   2048
#define BATCH 2
#define NH    16
#define HD    64
#define BM 128
#define BN 64
#define BK 32

typedef __attribute__((ext_vector_type(8))) short bf16x8;
typedef __attribute__((ext_vector_type(4))) short bf16x4;
typedef __attribute__((ext_vector_type(4))) float f32x4;

__device__ inline unsigned short f2bf(float f) {
  unsigned int u = __builtin_bit_cast(unsigned int, f);
  u += 0x7fffu + ((u >> 16) & 1u);
  return (unsigned short)(u >> 16);
}
__device__ inline float bf2f(unsigned short s) {
  unsigned int u = ((unsigned int)s) << 16;
  return __builtin_bit_cast(float, u);
}
// fast round-to-nearest (ties-away) f32->bf16 for P (2 VALU ops; bias negligible, p>=0)
__device__ inline short f2bf_fast(float f) {
  unsigned int u = __builtin_bit_cast(unsigned int, f);
  return (short)((u + 0x8000u) >> 16);
}

__device__ inline void async_cp16(const void* g, void* l) {
  __builtin_amdgcn_global_load_lds(
      (const __attribute__((address_space(1))) unsigned int*)g,
      (__attribute__((address_space(3))) unsigned int*)l, 16, 0, 0);
}

// ---- dtype sniff ----
__global__ void detect_kernel(const unsigned int* __restrict__ xq, int* __restrict__ flag) {
  __shared__ int cnt[256];
  int t = threadIdx.x;
  unsigned int w = xq[t];
  unsigned int e = (w >> 7) & 0xFFu;
  cnt[t] = (e >= 0x70u && e <= 0x8Fu) ? 1 : 0;
  __syncthreads();
  for (int s = 128; s > 0; s >>= 1) {
    if (t < s) cnt[t] += cnt[t + s];
    __syncthreads();
  }
  if (t == 0) *flag = (cnt[0] >= 160) ? 1 : 0;
}

// ---- fused fp32->bf16 pack ----
struct PackPtrs {
  const void* src[7];
  unsigned short* dst[7];
};
__global__ __launch_bounds__(256) void pack_all(PackPtrs p, const int* __restrict__ flagp) {
  const bool isbf = (*flagp != 0);
  int ci = blockIdx.x * 256 + threadIdx.x;
  int t, rel;
  if (ci < 1572864) { t = ci / 524288; rel = ci - t * 524288; }
  else { int r = ci - 1572864; int w = r / 131072; t = 3 + w; rel = r - w * 131072; }
  size_t off = (size_t)rel * 8;
  unsigned short* d = p.dst[t] + off;
  if (isbf) {
    *(bf16x8*)d = *(const bf16x8*)((const unsigned short*)p.src[t] + off);
  } else {
    const float* s = (const float*)p.src[t] + off;
    bf16x8 v;
#pragma unroll
    for (int e = 0; e < 8; ++e) v[e] = (short)f2bf(s[e]);
    *(bf16x8*)d = v;
  }
}

// ---- m97-style tiled GEMM (unchanged from round 5) ----
__global__ __launch_bounds__(256) void gemm128(
    const unsigned short* __restrict__ A,
    const unsigned short* __restrict__ Bw,
    const void* __restrict__ bias,
    void* __restrict__ out,
    const int* __restrict__ flagp,
    int mode)
{
  __shared__ __align__(16) unsigned short As[BM * BK];
  __shared__ __align__(16) unsigned short Bs[BN * BK];
  __shared__ __align__(16) unsigned short Ts[BM * (BN + 2)];

  const int tid = threadIdx.x;
  const int lane = tid & 63;
  const int wave = tid >> 6;
  const int wm = wave >> 1, wn = wave & 1;
  const int q = lane >> 4, c = lane & 15;
  const int m0 = blockIdx.x * BM;
  const int n0 = blockIdx.y * BN;

  f32x4 acc[4][2];
#pragma unroll
  for (int i = 0; i < 4; ++i)
#pragma unroll
    for (int j = 0; j < 2; ++j) acc[i][j] = (f32x4){0.f, 0.f, 0.f, 0.f};

  for (int k0 = 0; k0 < EMBED; k0 += BK) {
    __syncthreads();
#pragma unroll
    for (int jj = 0; jj < 2; ++jj) {
      int ci = jj * 256 + tid;
      async_cp16(A + (size_t)(m0 + (ci >> 2)) * EMBED + k0 + (ci & 3) * 8,
                 (void*)(As + (jj * 256 + wave * 64) * 8));
    }
    async_cp16(Bw + (size_t)(n0 + (tid >> 2)) * EMBED + k0 + (tid & 3) * 8,
               (void*)(Bs + wave * 64 * 8));
    __syncthreads();

    bf16x8 af[4], bfr[2];
#pragma unroll
    for (int i = 0; i < 4; ++i)
      af[i] = *(const bf16x8*)(As + (wm * 64 + i * 16 + c) * BK + q * 8);
#pragma unroll
    for (int j = 0; j < 2; ++j)
      bfr[j] = *(const bf16x8*)(Bs + (wn * 32 + j * 16 + c) * BK + q * 8);
#pragma unroll
    for (int i = 0; i < 4; ++i)
#pragma unroll
      for (int j = 0; j < 2; ++j)
        acc[i][j] = __builtin_amdgcn_mfma_f32_16x16x32_bf16(af[i], bfr[j], acc[i][j], 0, 0, 0);
  }

  const bool isbf = (*flagp != 0);

  if (mode == 2) {
    __syncthreads();
#pragma unroll
    for (int i = 0; i < 4; ++i)
#pragma unroll
      for (int j = 0; j < 2; ++j)
#pragma unroll
        for (int r = 0; r < 4; ++r)
          Ts[(wm * 64 + i * 16 + q * 4 + r) * (BN + 2) + wn * 32 + j * 16 + c] =
              f2bf(acc[i][j][r]);
    __syncthreads();
    int d = tid >> 2;
    int sb = (tid & 3) * 32;
    int b = m0 >> 11, s0l = m0 & 2047;
    int h = blockIdx.y;
    unsigned short* dst = (unsigned short*)out +
        (size_t)((b * NH + h) * HD + d) * SEQ + s0l + sb;
#pragma unroll
    for (int g = 0; g < 4; ++g) {
      bf16x8 v;
#pragma unroll
      for (int e = 0; e < 8; ++e) v[e] = (short)Ts[(sb + g * 8 + e) * (BN + 2) + d];
      *(bf16x8*)(dst + g * 8) = v;
    }
  } else {
#pragma unroll
    for (int i = 0; i < 4; ++i)
#pragma unroll
      for (int j = 0; j < 2; ++j)
#pragma unroll
        for (int r = 0; r < 4; ++r) {
          int m = m0 + wm * 64 + i * 16 + q * 4 + r;
          int col = n0 + wn * 32 + j * 16 + c;
          float v = acc[i][j][r];
          if (mode == 0) {
            v += isbf ? bf2f(((const unsigned short*)bias)[col])
                      : ((const float*)bias)[col];
            if (isbf) ((unsigned short*)out)[(size_t)m * EMBED + col] = f2bf(v);
            else      ((float*)out)[(size_t)m * EMBED + col] = v;
          } else {
            int b = m >> 11, s = m & 2047, h = col >> 6, d = col & 63;
            ((unsigned short*)out)[(size_t)((b * NH + h) * SEQ + s) * HD + d] = f2bf(v);
          }
        }
  }
}

// ---- fallback GEMM (round-3 proven) ----
__device__ inline bf16x8 load8(const void* p, int idx, bool isbf) {
  if (isbf) return *(const bf16x8*)((const unsigned short*)p + idx);
  const float* f = (const float*)p + idx;
  bf16x8 r;
#pragma unroll
  for (int i = 0; i < 8; ++i) r[i] = (short)f2bf(f[i]);
  return r;
}
__global__ __launch_bounds__(256) void gemm_bt(
    const void* __restrict__ A, const void* __restrict__ Bw,
    const void* __restrict__ bias, void* __restrict__ out,
    const int* __restrict__ flagp, int mode)
{
  const bool isbf = (*flagp != 0);
  const bool a_isbf = isbf || (mode == 0);
  const int lane = threadIdx.x & 63;
  const int wave = threadIdx.x >> 6;
  const int tile = blockIdx.x * 4 + wave;
  const int mt = tile >> 4, nt = tile & 15;
  const int q = lane >> 4, c = lane & 15;
  const int m0 = mt * 16, n0 = nt * 64;

  f32x4 acc[4];
#pragma unroll
  for (int t = 0; t < 4; ++t) acc[t] = (f32x4){0.f, 0.f, 0.f, 0.f};

  for (int k0 = 0; k0 < EMBED; k0 += 32) {
    bf16x8 a = load8(A, (m0 + c) * EMBED + k0 + q * 8, a_isbf);
#pragma unroll
    for (int t = 0; t < 4; ++t) {
      bf16x8 b = load8(Bw, (n0 + t * 16 + c) * EMBED + k0 + q * 8, isbf);
      acc[t] = __builtin_amdgcn_mfma_f32_16x16x32_bf16(a, b, acc[t], 0, 0, 0);
    }
  }
#pragma unroll
  for (int t = 0; t < 4; ++t)
#pragma unroll
    for (int r = 0; r < 4; ++r) {
      float v = acc[t][r];
      int row = m0 + q * 4 + r, col = n0 + t * 16 + c;
      if (mode == 0) {
        v += isbf ? bf2f(((const unsigned short*)bias)[col]) : ((const float*)bias)[col];
        if (isbf) ((unsigned short*)out)[row * EMBED + col] = f2bf(v);
        else      ((float*)out)[row * EMBED + col] = v;
      } else {
        int b = row >> 11, s = row & 2047, h = col >> 6, d = col & 63;
        if (mode == 1) ((unsigned short*)out)[(((b * NH + h) * SEQ) + s) * HD + d] = f2bf(v);
        else           ((unsigned short*)out)[(((b * NH + h) * HD) + d) * SEQ + s] = f2bf(v);
      }
    }
}

// ---- flash attention v2 ----
// Grid (16, 16, 2), block 256 = 4 waves x 32 qrows = 128 qrows/block; 64-key tiles.
// Score MFMA (S^T = K*Q^T) C-layout: reg r of lane(quad,c) = P[qrow=c][key=s*16+quad*4+r]
// == A-operand element layout of PV (k-slot->key map free per quad). Fixed-shift softmax.
__global__ __launch_bounds__(256) void attn_kernel(
    const unsigned short* __restrict__ Qb,
    const unsigned short* __restrict__ Kb,
    const unsigned short* __restrict__ Vtb,
    unsigned short* __restrict__ Ob)
{
  __shared__ __align__(16) unsigned short Kt[64][72];   // 64 keys x 64 d (row 144B)
  __shared__ __align__(16) unsigned short Vt[64][72];   // 64 d x 64 keys (row 144B)

  const int tid = threadIdx.x;
  const int lane = tid & 63;
  const int wave = tid >> 6;
  const int q = lane >> 4, c = lane & 15;
  const int b = blockIdx.z, h = blockIdx.y;
  const int q0w = blockIdx.x * 128 + wave * 32;

  const unsigned short* Qh = Qb + ((size_t)(b * NH + h) * SEQ) * HD;
  const unsigned short* Kh = Kb + ((size_t)(b * NH + h) * SEQ) * HD;
  const unsigned short* Vh = Vtb + ((size_t)(b * NH + h) * HD) * SEQ;

  // Q B-operand frags for 2 q-subtiles (n=lane&15=qrow, k=d=quad*8+j), held all kernel
  bf16x8 qfl[2], qfh[2];
#pragma unroll
  for (int qs = 0; qs < 2; ++qs) {
    qfl[qs] = *(const bf16x8*)(Qh + (q0w + qs * 16 + c) * HD + q * 8);
    qfh[qs] = *(const bf16x8*)(Qh + (q0w + qs * 16 + c) * HD + 32 + q * 8);
  }

  f32x4 o[2][4];
#pragma unroll
  for (int qs = 0; qs < 2; ++qs)
#pragma unroll
    for (int t = 0; t < 4; ++t) o[qs][t] = (f32x4){0.f, 0.f, 0.f, 0.f};
  float l[2] = {0.f, 0.f};

  const float cs = 0.125f * 1.44269504088896340736f;   // (1/sqrt(64))*log2(e)
  const float SH = 8.0f;                                // fixed softmax shift (exp2 domain)

  const int r0  = tid >> 3;         // 0..31
  const int ch0 = (tid & 7) * 8;    // 8-elem chunk within 64

  for (int kt = 0; kt < SEQ / 64; ++kt) {
    __syncthreads();
    *(bf16x8*)(&Kt[r0][ch0])      = *(const bf16x8*)(Kh + (size_t)(kt * 64 + r0) * HD + ch0);
    *(bf16x8*)(&Kt[32 + r0][ch0]) = *(const bf16x8*)(Kh + (size_t)(kt * 64 + 32 + r0) * HD + ch0);
    *(bf16x8*)(&Vt[r0][ch0])      = *(const bf16x8*)(Vh + (size_t)r0 * SEQ + kt * 64 + ch0);
    *(bf16x8*)(&Vt[32 + r0][ch0]) = *(const bf16x8*)(Vh + (size_t)(32 + r0) * SEQ + kt * 64 + ch0);
    __syncthreads();

#pragma unroll
    for (int g = 0; g < 2; ++g) {            // two 32-key groups
      bf16x4 pk[2][2];                       // [qs][s2] packed P (A-frag halves)
#pragma unroll
      for (int s2 = 0; s2 < 2; ++s2) {       // two 16-key subtiles per group
        const int s = g * 2 + s2;
        bf16x8 k0f = *(const bf16x8*)(&Kt[s * 16 + c][q * 8]);
        bf16x8 k1f = *(const bf16x8*)(&Kt[s * 16 + c][32 + q * 8]);
#pragma unroll
        for (int qs = 0; qs < 2; ++qs) {
          f32x4 z = {0.f, 0.f, 0.f, 0.f};
          z = __builtin_amdgcn_mfma_f32_16x16x32_bf16(k0f, qfl[qs], z, 0, 0, 0);
          z = __builtin_amdgcn_mfma_f32_16x16x32_bf16(k1f, qfh[qs], z, 0, 0, 0);
#pragma unroll
          for (int r = 0; r < 4; ++r) {
            float pv = __builtin_amdgcn_exp2f(z[r] * cs - SH);
            l[qs] += pv;
            pk[qs][s2][r] = f2bf_fast(pv);
          }
        }
      }
      // PV: one full 16x16x32 per (qs, d-tile); A = concat(sub0, sub1) P regs.
#pragma unroll
      for (int t = 0; t < 4; ++t) {
        bf16x4 v0 = *(const bf16x4*)(&Vt[t * 16 + c][g * 32 + q * 4]);
        bf16x4 v1 = *(const bf16x4*)(&Vt[t * 16 + c][g * 32 + 16 + q * 4]);
        bf16x8 vf;
#pragma unroll
        for (int e = 0; e < 4; ++e) { vf[e] = v0[e]; vf[4 + e] = v1[e]; }
#pragma unroll
        for (int qs = 0; qs < 2; ++qs) {
          bf16x8 pf;
#pragma unroll
          for (int e = 0; e < 4; ++e) { pf[e] = pk[qs][0][e]; pf[4 + e] = pk[qs][1][e]; }
          o[qs][t] = __builtin_amdgcn_mfma_f32_16x16x32_bf16(pf, vf, o[qs][t], 0, 0, 0);
        }
      }
    }
  }

#pragma unroll
  for (int qs = 0; qs < 2; ++qs) {
    float ls = l[qs];
    ls += __shfl_xor(ls, 16);
    ls += __shfl_xor(ls, 32);
    float lf[4];
#pragma unroll
    for (int r = 0; r < 4; ++r) lf[r] = 1.f / __shfl(ls, q * 4 + r);
#pragma unroll
    for (int t = 0; t < 4; ++t)
#pragma unroll
      for (int r = 0; r < 4; ++r) {
        int srow = q0w + qs * 16 + q * 4 + r;
        int col = h * HD + t * 16 + c;
        float val = o[qs][t][r] * lf[r];
        if (isnan(val)) val = 77.0f;
        Ob[((size_t)(b * SEQ + srow)) * EMBED + col] = f2bf(val);
      }
  }
}

extern "C" void kernel_launch(void* const* d_in, const int* in_sizes, int n_in,
                              void* d_out, int out_size, void* d_ws, size_t ws_size,
                              hipStream_t stream) {
  const void* xq = d_in[0]; const void* xk = d_in[1]; const void* xv = d_in[2];
  const void* Wq = d_in[3]; const void* Wk = d_in[4]; const void* Wv = d_in[5];
  const void* Wo = d_in[6]; const void* bo = d_in[7];

  const size_t NEL = (size_t)BATCH * SEQ * EMBED;
  const size_t WEL = (size_t)EMBED * EMBED;
  unsigned short* base = (unsigned short*)d_ws;

  unsigned short* Xq = base;
  unsigned short* Xk = Xq + NEL;
  unsigned short* Xv = Xk + NEL;
  unsigned short* Wqb = Xv + NEL;
  unsigned short* Wkb = Wqb + WEL;
  unsigned short* Wvb = Wkb + WEL;
  unsigned short* Wob = Wvb + WEL;
  unsigned short* Q  = Wob + WEL;
  unsigned short* K  = Q + NEL;
  unsigned short* Vt = K + NEL;
  unsigned short* AO = Xq;                  // alias: Xq dead after its GEMM
  int* flagF = (int*)(Vt + NEL);
  size_t need = ((char*)(flagF + 16)) - (char*)d_ws;

  if (ws_size >= need) {
    detect_kernel<<<1, 256, 0, stream>>>((const unsigned int*)xq, flagF);
    PackPtrs pp;
    pp.src[0] = xq; pp.src[1] = xk; pp.src[2] = xv;
    pp.src[3] = Wq; pp.src[4] = Wk; pp.src[5] = Wv; pp.src[6] = Wo;
    pp.dst[0] = Xq; pp.dst[1] = Xk; pp.dst[2] = Xv;
    pp.dst[3] = Wqb; pp.dst[4] = Wkb; pp.dst[5] = Wvb; pp.dst[6] = Wob;
    pack_all<<<8192, 256, 0, stream>>>(pp, flagF);
    dim3 gg(32, 16);
    gemm128<<<gg, 256, 0, stream>>>(Xq, Wqb, nullptr, Q, flagF, 1);
    gemm128<<<gg, 256, 0, stream>>>(Xk, Wkb, nullptr, K, flagF, 1);
    gemm128<<<gg, 256, 0, stream>>>(Xv, Wvb, nullptr, Vt, flagF, 2);
    attn_kernel<<<dim3(16, NH, BATCH), 256, 0, stream>>>(Q, K, Vt, AO);
    gemm128<<<gg, 256, 0, stream>>>(AO, Wob, bo, d_out, flagF, 0);
  } else {
    unsigned short* Qf  = base;
    unsigned short* Kf  = Qf + NEL;
    unsigned short* Vtf = Kf + NEL;
    unsigned short* AOf = Vtf + NEL;
    int* flag = (int*)(AOf + NEL);
    detect_kernel<<<1, 256, 0, stream>>>((const unsigned int*)xq, flag);
    dim3 gblk(1024, 1, 1);
    gemm_bt<<<gblk, 256, 0, stream>>>(xq, Wq, nullptr, Qf, flag, 1);
    gemm_bt<<<gblk, 256, 0, stream>>>(xk, Wk, nullptr, Kf, flag, 1);
    gemm_bt<<<gblk, 256, 0, stream>>>(xv, Wv, nullptr, Vtf, flag, 2);
    attn_kernel<<<dim3(16, NH, BATCH), 256, 0, stream>>>(Qf, Kf, Vtf, AOf);
    gemm_bt<<<gblk, 256, 0, stream>>>(AOf, Wo, bo, d_out, flag, 0);
  }
}

// Round 7
// 254.760 us; speedup vs baseline: 3.0284x; 1.0555x over previous
//
#include <hip/hip_runtime.h>
#include <math.h>

// MultiHeadAttentionEinsum  B=2, S=2048, E=1024, H=16, D=64. Inputs fp32
// (confirmed; bf16-sniff kept as insurance). Compute bf16 MFMA.
// r7: fused-QKV 128x128 m97 GEMM (z-grid), dbuf attn with 4 blocks/CU,
// softmax scale folded into Q projection.

#define EMBED 1024
#define SEQ   2048
#define BATCH 2
#define NH    16
#define HD    64

typedef __attribute__((ext_vector_type(8))) short bf16x8;
typedef __attribute__((ext_vector_type(4))) short bf16x4;
typedef __attribute__((ext_vector_type(4))) float f32x4;

#define QSCALE 0.18033688f   // (1/sqrt(64)) * log2(e), folded into Q projection

__device__ inline unsigned short f2bf(float f) {
  unsigned int u = __builtin_bit_cast(unsigned int, f);
  u += 0x7fffu + ((u >> 16) & 1u);
  return (unsigned short)(u >> 16);
}
__device__ inline float bf2f(unsigned short s) {
  unsigned int u = ((unsigned int)s) << 16;
  return __builtin_bit_cast(float, u);
}

__device__ inline void async_cp16(const void* g, void* l) {
  __builtin_amdgcn_global_load_lds(
      (const __attribute__((address_space(1))) unsigned int*)g,
      (__attribute__((address_space(3))) unsigned int*)l, 16, 0, 0);
}

// ---- dtype sniff ----
__global__ void detect_kernel(const unsigned int* __restrict__ xq, int* __restrict__ flag) {
  __shared__ int cnt[256];
  int t = threadIdx.x;
  unsigned int w = xq[t];
  unsigned int e = (w >> 7) & 0xFFu;
  cnt[t] = (e >= 0x70u && e <= 0x8Fu) ? 1 : 0;
  __syncthreads();
  for (int s = 128; s > 0; s >>= 1) {
    if (t < s) cnt[t] += cnt[t + s];
    __syncthreads();
  }
  if (t == 0) *flag = (cnt[0] >= 160) ? 1 : 0;
}

// ---- fused fp32->bf16 pack ----
struct PackPtrs {
  const void* src[7];
  unsigned short* dst[7];
};
__global__ __launch_bounds__(256) void pack_all(PackPtrs p, const int* __restrict__ flagp) {
  const bool isbf = (*flagp != 0);
  int ci = blockIdx.x * 256 + threadIdx.x;
  int t, rel;
  if (ci < 1572864) { t = ci / 524288; rel = ci - t * 524288; }
  else { int r = ci - 1572864; int w = r / 131072; t = 3 + w; rel = r - w * 131072; }
  size_t off = (size_t)rel * 8;
  unsigned short* d = p.dst[t] + off;
  if (isbf) {
    *(bf16x8*)d = *(const bf16x8*)((const unsigned short*)p.src[t] + off);
  } else {
    const float* s = (const float*)p.src[t] + off;
    bf16x8 v;
#pragma unroll
    for (int e = 0; e < 8; ++e) v[e] = (short)f2bf(s[e]);
    *(bf16x8*)d = v;
  }
}

// ---- fused QKV GEMM: 128x128 tile (m97 structure), grid (32, 8, 3) ----
// z=0: Q out [B,H,S,D] * QSCALE; z=1: K out [B,H,S,D]; z=2: V out [B,H,D,S]
struct QkvArgs {
  const unsigned short* A[3];
  const unsigned short* W[3];
  unsigned short* out[3];
};
__global__ __launch_bounds__(256) void gemm_qkv(QkvArgs args) {
  __shared__ __align__(16) unsigned short smem[16640];  // As 4096 | Bs 4096 ; Ts reuses all
  unsigned short* As = smem;
  unsigned short* Bs = smem + 4096;

  const int z = blockIdx.z;
  const unsigned short* A = args.A[z];
  const unsigned short* Bw = args.W[z];
  unsigned short* out = args.out[z];

  const int tid = threadIdx.x, lane = tid & 63, wave = tid >> 6;
  const int wm = wave >> 1, wn = wave & 1;
  const int q = lane >> 4, c = lane & 15;
  const int m0 = blockIdx.x * 128, n0 = blockIdx.y * 128;

  f32x4 acc[4][4];
#pragma unroll
  for (int i = 0; i < 4; ++i)
#pragma unroll
    for (int j = 0; j < 4; ++j) acc[i][j] = (f32x4){0.f, 0.f, 0.f, 0.f};

  for (int k0 = 0; k0 < EMBED; k0 += 32) {
    __syncthreads();
#pragma unroll
    for (int jj = 0; jj < 2; ++jj) {
      int ci = jj * 256 + tid;
      async_cp16(A + (size_t)(m0 + (ci >> 2)) * EMBED + k0 + (ci & 3) * 8,
                 (void*)(As + (jj * 256 + wave * 64) * 8));
      async_cp16(Bw + (size_t)(n0 + (ci >> 2)) * EMBED + k0 + (ci & 3) * 8,
                 (void*)(Bs + (jj * 256 + wave * 64) * 8));
    }
    __syncthreads();

    bf16x8 af[4], bfr[4];
#pragma unroll
    for (int i = 0; i < 4; ++i)
      af[i] = *(const bf16x8*)(As + (wm * 64 + i * 16 + c) * 32 + q * 8);
#pragma unroll
    for (int j = 0; j < 4; ++j)
      bfr[j] = *(const bf16x8*)(Bs + (wn * 64 + j * 16 + c) * 32 + q * 8);
#pragma unroll
    for (int i = 0; i < 4; ++i)
#pragma unroll
      for (int j = 0; j < 4; ++j)
        acc[i][j] = __builtin_amdgcn_mfma_f32_16x16x32_bf16(af[i], bfr[j], acc[i][j], 0, 0, 0);
  }

  if (z < 2) {
    const float sc = (z == 0) ? QSCALE : 1.0f;
#pragma unroll
    for (int i = 0; i < 4; ++i)
#pragma unroll
      for (int j = 0; j < 4; ++j)
#pragma unroll
        for (int r = 0; r < 4; ++r) {
          int m = m0 + wm * 64 + i * 16 + q * 4 + r;
          int col = n0 + wn * 64 + j * 16 + c;
          int b = m >> 11, s = m & 2047, h = col >> 6, d = col & 63;
          out[(size_t)((b * NH + h) * SEQ + s) * HD + d] = f2bf(acc[i][j][r] * sc);
        }
  } else {
    // V: transpose 128(s) x 128(d, 2 heads) tile through LDS -> [B,H,D,S]
    __syncthreads();
#pragma unroll
    for (int i = 0; i < 4; ++i)
#pragma unroll
      for (int j = 0; j < 4; ++j)
#pragma unroll
        for (int r = 0; r < 4; ++r)
          smem[(wm * 64 + i * 16 + q * 4 + r) * 130 + wn * 64 + j * 16 + c] =
              f2bf(acc[i][j][r]);
    __syncthreads();
    int n = tid >> 1;                 // 0..127 local d-col
    int sh = (tid & 1) * 64;          // s half
    int b = m0 >> 11, s0l = m0 & 2047;
    int h = blockIdx.y * 2 + (n >> 6), d = n & 63;
    unsigned short* dst = out + (size_t)((b * NH + h) * HD + d) * SEQ + s0l + sh;
#pragma unroll
    for (int g = 0; g < 8; ++g) {
      bf16x8 v;
#pragma unroll
      for (int e = 0; e < 8; ++e) v[e] = (short)smem[(sh + g * 8 + e) * 130 + n];
      *(bf16x8*)(dst + g * 8) = v;
    }
  }
}

// ---- out-projection GEMM: 128x128 tile, grid (32, 8) ----
__global__ __launch_bounds__(256) void gemm_out(
    const unsigned short* __restrict__ A,
    const unsigned short* __restrict__ Bw,
    const void* __restrict__ bias,
    void* __restrict__ out,
    const int* __restrict__ flagp)
{
  __shared__ __align__(16) unsigned short As[4096];
  __shared__ __align__(16) unsigned short Bs[4096];

  const int tid = threadIdx.x, lane = tid & 63, wave = tid >> 6;
  const int wm = wave >> 1, wn = wave & 1;
  const int q = lane >> 4, c = lane & 15;
  const int m0 = blockIdx.x * 128, n0 = blockIdx.y * 128;

  f32x4 acc[4][4];
#pragma unroll
  for (int i = 0; i < 4; ++i)
#pragma unroll
    for (int j = 0; j < 4; ++j) acc[i][j] = (f32x4){0.f, 0.f, 0.f, 0.f};

  for (int k0 = 0; k0 < EMBED; k0 += 32) {
    __syncthreads();
#pragma unroll
    for (int jj = 0; jj < 2; ++jj) {
      int ci = jj * 256 + tid;
      async_cp16(A + (size_t)(m0 + (ci >> 2)) * EMBED + k0 + (ci & 3) * 8,
                 (void*)(As + (jj * 256 + wave * 64) * 8));
      async_cp16(Bw + (size_t)(n0 + (ci >> 2)) * EMBED + k0 + (ci & 3) * 8,
                 (void*)(Bs + (jj * 256 + wave * 64) * 8));
    }
    __syncthreads();

    bf16x8 af[4], bfr[4];
#pragma unroll
    for (int i = 0; i < 4; ++i)
      af[i] = *(const bf16x8*)(As + (wm * 64 + i * 16 + c) * 32 + q * 8);
#pragma unroll
    for (int j = 0; j < 4; ++j)
      bfr[j] = *(const bf16x8*)(Bs + (wn * 64 + j * 16 + c) * 32 + q * 8);
#pragma unroll
    for (int i = 0; i < 4; ++i)
#pragma unroll
      for (int j = 0; j < 4; ++j)
        acc[i][j] = __builtin_amdgcn_mfma_f32_16x16x32_bf16(af[i], bfr[j], acc[i][j], 0, 0, 0);
  }

  const bool isbf = (*flagp != 0);
#pragma unroll
  for (int i = 0; i < 4; ++i)
#pragma unroll
    for (int j = 0; j < 4; ++j)
#pragma unroll
      for (int r = 0; r < 4; ++r) {
        int m = m0 + wm * 64 + i * 16 + q * 4 + r;
        int col = n0 + wn * 64 + j * 16 + c;
        float v = acc[i][j][r];
        v += isbf ? bf2f(((const unsigned short*)bias)[col]) : ((const float*)bias)[col];
        if (isnan(v)) v = 777.0f;     // marker
        if (isbf) ((unsigned short*)out)[(size_t)m * EMBED + col] = f2bf(v);
        else      ((float*)out)[(size_t)m * EMBED + col] = v;
      }
}

// ---- flash attention v3: grid (32,16,2)=1024 blocks, 4 waves x 16 qrows ----
// Q pre-scaled by QSCALE -> p = exp2(z), no shift (z<=~6, no overflow; renorm by l).
// Double-buffered K/V tiles (64 keys); score C-layout feeds PV A-operand directly.
__global__ __launch_bounds__(256) void attn_kernel(
    const unsigned short* __restrict__ Qb,
    const unsigned short* __restrict__ Kb,
    const unsigned short* __restrict__ Vtb,
    unsigned short* __restrict__ Ob)
{
  __shared__ __align__(16) unsigned short Kt[2][64][72];
  __shared__ __align__(16) unsigned short Vs[2][64][72];

  const int tid = threadIdx.x;
  const int lane = tid & 63;
  const int wave = tid >> 6;
  const int q = lane >> 4, c = lane & 15;
  const int b = blockIdx.z, h = blockIdx.y;
  const int q0 = blockIdx.x * 64 + wave * 16;

  const unsigned short* Qh = Qb + ((size_t)(b * NH + h) * SEQ) * HD;
  const unsigned short* Kh = Kb + ((size_t)(b * NH + h) * SEQ) * HD;
  const unsigned short* Vh = Vtb + ((size_t)(b * NH + h) * HD) * SEQ;

  // Q B-operand frags (n=lane&15=qrow, k=d=quad*8+j)
  bf16x8 qfl = *(const bf16x8*)(Qh + (q0 + c) * HD + q * 8);
  bf16x8 qfh = *(const bf16x8*)(Qh + (q0 + c) * HD + 32 + q * 8);

  f32x4 o[4];
#pragma unroll
  for (int t = 0; t < 4; ++t) o[t] = (f32x4){0.f, 0.f, 0.f, 0.f};
  float l = 0.f;

  const int r0 = tid >> 3;          // 0..31
  const int ch0 = (tid & 7) * 8;    // 8-elem chunk

  bf16x8 kr0, kr1, vr0, vr1;
  // prefetch + stage tile 0
  kr0 = *(const bf16x8*)(Kh + (size_t)r0 * HD + ch0);
  kr1 = *(const bf16x8*)(Kh + (size_t)(32 + r0) * HD + ch0);
  vr0 = *(const bf16x8*)(Vh + (size_t)r0 * SEQ + ch0);
  vr1 = *(const bf16x8*)(Vh + (size_t)(32 + r0) * SEQ + ch0);
  *(bf16x8*)(&Kt[0][r0][ch0]) = kr0;
  *(bf16x8*)(&Kt[0][32 + r0][ch0]) = kr1;
  *(bf16x8*)(&Vs[0][r0][ch0]) = vr0;
  *(bf16x8*)(&Vs[0][32 + r0][ch0]) = vr1;

  for (int kt = 0; kt < SEQ / 64; ++kt) {
    const int p = kt & 1;
    __syncthreads();
    if (kt + 1 < SEQ / 64) {        // issue next-tile loads early (latency overlap)
      kr0 = *(const bf16x8*)(Kh + (size_t)((kt + 1) * 64 + r0) * HD + ch0);
      kr1 = *(const bf16x8*)(Kh + (size_t)((kt + 1) * 64 + 32 + r0) * HD + ch0);
      vr0 = *(const bf16x8*)(Vh + (size_t)r0 * SEQ + (kt + 1) * 64 + ch0);
      vr1 = *(const bf16x8*)(Vh + (size_t)(32 + r0) * SEQ + (kt + 1) * 64 + ch0);
    }

#pragma unroll
    for (int g = 0; g < 2; ++g) {
      bf16x4 pk[2];
#pragma unroll
      for (int s2 = 0; s2 < 2; ++s2) {
        const int s = g * 2 + s2;
        bf16x8 k0f = *(const bf16x8*)(&Kt[p][s * 16 + c][q * 8]);
        bf16x8 k1f = *(const bf16x8*)(&Kt[p][s * 16 + c][32 + q * 8]);
        f32x4 z = {0.f, 0.f, 0.f, 0.f};
        z = __builtin_amdgcn_mfma_f32_16x16x32_bf16(k0f, qfl, z, 0, 0, 0);
        z = __builtin_amdgcn_mfma_f32_16x16x32_bf16(k1f, qfh, z, 0, 0, 0);
#pragma unroll
        for (int r = 0; r < 4; ++r) {
          float pv = __builtin_amdgcn_exp2f(z[r]);
          l += pv;
          pk[s2][r] = (short)(__builtin_bit_cast(unsigned int, pv) >> 16);  // trunc pack
        }
      }
#pragma unroll
      for (int t = 0; t < 4; ++t) {
        bf16x4 v0 = *(const bf16x4*)(&Vs[p][t * 16 + c][g * 32 + q * 4]);
        bf16x4 v1 = *(const bf16x4*)(&Vs[p][t * 16 + c][g * 32 + 16 + q * 4]);
        bf16x8 vf, pf;
#pragma unroll
        for (int e = 0; e < 4; ++e) {
          vf[e] = v0[e]; vf[4 + e] = v1[e];
          pf[e] = pk[0][e]; pf[4 + e] = pk[1][e];
        }
        o[t] = __builtin_amdgcn_mfma_f32_16x16x32_bf16(pf, vf, o[t], 0, 0, 0);
      }
    }

    if (kt + 1 < SEQ / 64) {        // stage next tile into the other buffer
      *(bf16x8*)(&Kt[1 - p][r0][ch0]) = kr0;
      *(bf16x8*)(&Kt[1 - p][32 + r0][ch0]) = kr1;
      *(bf16x8*)(&Vs[1 - p][r0][ch0]) = vr0;
      *(bf16x8*)(&Vs[1 - p][32 + r0][ch0]) = vr1;
    }
  }

  float ls = l;
  ls += __shfl_xor(ls, 16);
  ls += __shfl_xor(ls, 32);
  float lf[4];
#pragma unroll
  for (int r = 0; r < 4; ++r) lf[r] = 1.f / __shfl(ls, q * 4 + r);
#pragma unroll
  for (int t = 0; t < 4; ++t)
#pragma unroll
    for (int r = 0; r < 4; ++r) {
      int srow = q0 + q * 4 + r;
      int col = h * HD + t * 16 + c;
      float val = o[t][r] * lf[r];
      if (isnan(val)) val = 77.0f;  // marker
      Ob[((size_t)(b * SEQ + srow)) * EMBED + col] = f2bf(val);
    }
}

// ---- fallback GEMM (round-3 proven, direct global loads) ----
__device__ inline bf16x8 load8(const void* p, int idx, bool isbf) {
  if (isbf) return *(const bf16x8*)((const unsigned short*)p + idx);
  const float* f = (const float*)p + idx;
  bf16x8 r;
#pragma unroll
  for (int i = 0; i < 8; ++i) r[i] = (short)f2bf(f[i]);
  return r;
}
__global__ __launch_bounds__(256) void gemm_bt(
    const void* __restrict__ A, const void* __restrict__ Bw,
    const void* __restrict__ bias, void* __restrict__ out,
    const int* __restrict__ flagp, int mode, float scale)
{
  const bool isbf = (*flagp != 0);
  const bool a_isbf = isbf || (mode == 0);
  const int lane = threadIdx.x & 63;
  const int wave = threadIdx.x >> 6;
  const int tile = blockIdx.x * 4 + wave;
  const int mt = tile >> 4, nt = tile & 15;
  const int q = lane >> 4, c = lane & 15;
  const int m0 = mt * 16, n0 = nt * 64;

  f32x4 acc[4];
#pragma unroll
  for (int t = 0; t < 4; ++t) acc[t] = (f32x4){0.f, 0.f, 0.f, 0.f};

  for (int k0 = 0; k0 < EMBED; k0 += 32) {
    bf16x8 a = load8(A, (m0 + c) * EMBED + k0 + q * 8, a_isbf);
#pragma unroll
    for (int t = 0; t < 4; ++t) {
      bf16x8 b = load8(Bw, (n0 + t * 16 + c) * EMBED + k0 + q * 8, isbf);
      acc[t] = __builtin_amdgcn_mfma_f32_16x16x32_bf16(a, b, acc[t], 0, 0, 0);
    }
  }
#pragma unroll
  for (int t = 0; t < 4; ++t)
#pragma unroll
    for (int r = 0; r < 4; ++r) {
      float v = acc[t][r] * scale;
      int row = m0 + q * 4 + r, col = n0 + t * 16 + c;
      if (mode == 0) {
        v += isbf ? bf2f(((const unsigned short*)bias)[col]) : ((const float*)bias)[col];
        if (isbf) ((unsigned short*)out)[row * EMBED + col] = f2bf(v);
        else      ((float*)out)[row * EMBED + col] = v;
      } else {
        int b = row >> 11, s = row & 2047, h = col >> 6, d = col & 63;
        if (mode == 1) ((unsigned short*)out)[(((b * NH + h) * SEQ) + s) * HD + d] = f2bf(v);
        else           ((unsigned short*)out)[(((b * NH + h) * HD) + d) * SEQ + s] = f2bf(v);
      }
    }
}

extern "C" void kernel_launch(void* const* d_in, const int* in_sizes, int n_in,
                              void* d_out, int out_size, void* d_ws, size_t ws_size,
                              hipStream_t stream) {
  const void* xq = d_in[0]; const void* xk = d_in[1]; const void* xv = d_in[2];
  const void* Wq = d_in[3]; const void* Wk = d_in[4]; const void* Wv = d_in[5];
  const void* Wo = d_in[6]; const void* bo = d_in[7];

  const size_t NEL = (size_t)BATCH * SEQ * EMBED;
  const size_t WEL = (size_t)EMBED * EMBED;
  unsigned short* base = (unsigned short*)d_ws;

  unsigned short* Xq = base;
  unsigned short* Xk = Xq + NEL;
  unsigned short* Xv = Xk + NEL;
  unsigned short* Wqb = Xv + NEL;
  unsigned short* Wkb = Wqb + WEL;
  unsigned short* Wvb = Wkb + WEL;
  unsigned short* Wob = Wvb + WEL;
  unsigned short* Q  = Wob + WEL;
  unsigned short* K  = Q + NEL;
  unsigned short* Vt = K + NEL;
  unsigned short* AO = Xq;                  // alias: Xq dead after QKV GEMM
  int* flagF = (int*)(Vt + NEL);
  size_t need = ((char*)(flagF + 16)) - (char*)d_ws;

  if (ws_size >= need) {
    detect_kernel<<<1, 256, 0, stream>>>((const unsigned int*)xq, flagF);
    PackPtrs pp;
    pp.src[0] = xq; pp.src[1] = xk; pp.src[2] = xv;
    pp.src[3] = Wq; pp.src[4] = Wk; pp.src[5] = Wv; pp.src[6] = Wo;
    pp.dst[0] = Xq; pp.dst[1] = Xk; pp.dst[2] = Xv;
    pp.dst[3] = Wqb; pp.dst[4] = Wkb; pp.dst[5] = Wvb; pp.dst[6] = Wob;
    pack_all<<<8192, 256, 0, stream>>>(pp, flagF);

    QkvArgs qa;
    qa.A[0] = Xq; qa.A[1] = Xk; qa.A[2] = Xv;
    qa.W[0] = Wqb; qa.W[1] = Wkb; qa.W[2] = Wvb;
    qa.out[0] = Q; qa.out[1] = K; qa.out[2] = Vt;
    gemm_qkv<<<dim3(32, 8, 3), 256, 0, stream>>>(qa);
    attn_kernel<<<dim3(32, NH, BATCH), 256, 0, stream>>>(Q, K, Vt, AO);
    gemm_out<<<dim3(32, 8), 256, 0, stream>>>(AO, Wob, bo, d_out, flagF);
  } else {
    unsigned short* Qf  = base;
    unsigned short* Kf  = Qf + NEL;
    unsigned short* Vtf = Kf + NEL;
    unsigned short* AOf = Vtf + NEL;
    int* flag = (int*)(AOf + NEL);
    detect_kernel<<<1, 256, 0, stream>>>((const unsigned int*)xq, flag);
    dim3 gblk(1024, 1, 1);
    gemm_bt<<<gblk, 256, 0, stream>>>(xq, Wq, nullptr, Qf, flag, 1, QSCALE);
    gemm_bt<<<gblk, 256, 0, stream>>>(xk, Wk, nullptr, Kf, flag, 1, 1.0f);
    gemm_bt<<<gblk, 256, 0, stream>>>(xv, Wv, nullptr, Vtf, flag, 2, 1.0f);
    attn_kernel<<<dim3(32, NH, BATCH), 256, 0, stream>>>(Qf, Kf, Vtf, AOf);
    gemm_bt<<<gblk, 256, 0, stream>>>(AOf, Wo, bo, d_out, flag, 0, 1.0f);
  }
}